// Round 6
// baseline (153.519 us; speedup 1.0000x reference)
//
#include <hip/hip_runtime.h>
#include <hip/hip_bf16.h>

// z: (8,2048,64) f32 -> N=16384, D=64 ; codebook: (8192,64) f32
// outputs (f32, concat): z_q_st[1048576], vq_loss[1], idx[16384],
//   new_codebook[524288], new_cs[8192], new_ws[524288]
//
// Distance argmin via f16-split MFMA: x = xh + xl. dot(x,c) ~= Xh.Ch + Xh.Cl
// + Xl.Ch. argmin ||x-c||^2 == argmax (dot - 0.5||c||^2); -0.5||c||^2 is
// folded into the first MFMA's C operand. Codebook preprocessed ONCE into a
// swizzled f16-split image (k_prep) -> k_mfma stages via global_load_lds.
//
// R6: 4-way query register blocking. R0/R2/R5 showed residency pins at ~3
// blocks/CU regardless of LDS, and per-wave MFMA duty is ~50% (argmax VALU
// at parity with MFMA). Fix = more ILP per wave + fewer barriers per MFMA:
// each wave now owns 4 q-tiles (64 queries); per staged tile, 24 MFMAs in 4
// independent 6-chains share one ds_read set (was 12/2). GROUP=64 (proven
// best cadence), NSPLIT=16 -> 1024 blocks; staging traffic halves. acc init
// via first-MFMA C=ncv (D!=C, no per-qt movs). launch_bounds (256,3): VGPR
// cap 170 >> natural ~135 (R3/R4: tight caps collapse the allocator).

#define NQ 16384
#define KC 8192
#define DD 64
#define NSPLIT 16
#define CSPLIT (KC / NSPLIT)     // 512 codes per block job
#define GROUP 64                 // codes staged in LDS per barrier
#define NGROUP (CSPLIT / GROUP)  // 8
#define NTILE (GROUP / 16)       // 4 MFMA c-tiles per staged group
#define IMGH 8192                // halves per group image (16 KB)

typedef _Float16 half8 __attribute__((ext_vector_type(8)));
typedef _Float16 half4v __attribute__((ext_vector_type(4)));
typedef float f32x4 __attribute__((ext_vector_type(4)));
typedef unsigned int u32;

__device__ __forceinline__ void async_copy16(const _Float16* g, _Float16* l) {
  __builtin_amdgcn_global_load_lds(
      (const __attribute__((address_space(1))) u32*)(const void*)g,
      (__attribute__((address_space(3))) u32*)(void*)l, 16, 0, 0);
}

// ---------------- workspace layout (floats) ----------------
// [0)        nhcn    8192    (-0.5*||c||^2)
// [8192)     epart   32      (ema_cs partial sums, non-atomic)
// [8224)     parts   1024    (loss partials, one per k_assign block)
// [16384)    pmax    262144  (16 x 16384 partial max-u)
// [278528)   pidx    262144 u16 = 131072 f32
// [409600)   cnt     8192    (int, atomic counts)
// [417792)   dw      524288  (atomic scatter sums)
// [942080)   Cxs     524288  f32 = 1048576 halves (128 group images x 16 KB)

// k_prep: swizzled f16-split codebook image + nhcn + ema partials + zeroing
// of the dw/cnt atomic accumulators.
// thread = (code c, j4) ; c = gid>>4, j4 = gid&15 covers f32x4 d=4*j4..
__global__ __launch_bounds__(256) void k_prep(
    const float* __restrict__ cb, const float* __restrict__ ema_cs,
    _Float16* __restrict__ Cxs, float* __restrict__ nhcn,
    float* __restrict__ epart, float* __restrict__ dw, int* __restrict__ cnt) {
  const int t = threadIdx.x;
  const int gid = blockIdx.x * 256 + t;
  const int c = gid >> 4;
  const int j4 = gid & 15;

  // zero atomic accumulators for this iteration
  ((f32x4*)dw)[gid] = f32x4{0.f, 0.f, 0.f, 0.f};
  if (gid < KC) cnt[gid] = 0;

  const f32x4 v = ((const f32x4*)cb)[gid];
  half4v hh, ll;
  float s = 0.f;
#pragma unroll
  for (int e = 0; e < 4; ++e) {
    const float f = v[e];
    const _Float16 h = (_Float16)f;
    hh[e] = h;
    ll[e] = (_Float16)(f - (float)h);
    s = fmaf(f, f, s);
  }
  // swizzled slot (same formula as the LDS-consumer in k_mfma)
  const int r = c & (GROUP - 1);   // row in group
  const int tt = r >> 4;
  const int n = r & 15;
  const int q = (j4 >> 1) & 3;
  const int ihalf = j4 & 1;
  const int frh = j4 >> 3;
  const int fs = frh * 4 + q;
  const int nw = n ^ fs;
  _Float16* img = Cxs + (size_t)(c / GROUP) * IMGH;
  *(half4v*)(img + ((size_t)((tt * 4 + frh) * 64 + q * 16 + nw)) * 8 +
             ihalf * 4) = hh;
  *(half4v*)(img + ((size_t)((tt * 4 + frh + 2) * 64 + q * 16 + nw)) * 8 +
             ihalf * 4) = ll;

  // row sumsq: reduce across the 16 lanes of this row (lanes j4=0..15)
#pragma unroll
  for (int off = 1; off < 16; off <<= 1) s += __shfl_xor(s, off, 64);
  if (j4 == 0) nhcn[c] = -0.5f * s;

  // ema partials: blocks 0..31 each reduce 256 values (non-atomic write)
  if (blockIdx.x < 32) {
    float su = ema_cs[blockIdx.x * 256 + t];
#pragma unroll
    for (int off = 1; off < 64; off <<= 1) su += __shfl_xor(su, off, 64);
    __shared__ float ss[4];
    if ((t & 63) == 0) ss[t >> 6] = su;
    __syncthreads();
    if (t == 0) epart[blockIdx.x] = ss[0] + ss[1] + ss[2] + ss[3];
  }
}

// MFMA argmax. 256-thread block = 4 waves x 64 queries (4 q-tiles each);
// block job = 512 codes (split). Per staged 64-code group: 4 c-tiles, each
// feeding 4 independent 6-deep MFMA chains off one ds_read set. Double-
// buffered global_load_lds staging (16 KB images), counted vmcnt(4); nhcn
// staged once to LDS -> no VMEM in the K-loop besides the DMAs.
__global__ __launch_bounds__(256, 3) void k_mfma(
    const float* __restrict__ z, const _Float16* __restrict__ Cxs,
    const float* __restrict__ nhcn, float* __restrict__ pmax,
    unsigned short* __restrict__ pidx) {
  __shared__ _Float16 Bs[2 * IMGH];  // 32 KB (double buffer)
  __shared__ float nh[CSPLIT];       // 2 KB
  const int t = threadIdx.x;
  const int lane = t & 63;
  const int w = t >> 6;
  const int split = blockIdx.y;
  const int Qw = blockIdx.x * 256 + w * 64;
  const int n16 = lane & 15;
  const int quad = lane >> 4;

  // nhcn for this split -> LDS (two f32 per thread)
  const float nhv0 = nhcn[split * CSPLIT + t];
  const float nhv1 = nhcn[split * CSPLIT + 256 + t];

  // prologue: stage group 0 into buffer 0
  {
    const _Float16* gimg = Cxs + (size_t)(split * NGROUP) * IMGH;
#pragma unroll
    for (int p = 0; p < 4; ++p) {
      const int off = (t + 256 * p) * 8;  // halves
      async_copy16(gimg + off, Bs + off);
    }
  }
  nh[t] = nhv0;
  nh[t + 256] = nhv1;

  // A-frags: z rows -> f16 split in registers (layout: lane holds
  // A[m=lane&15][k=(lane>>4)*8+j]; frag hf covers k/d in [32*hf, 32*hf+32)).
  const f32x4* __restrict__ z4 = (const f32x4*)z;
  half8 aH0[4], aH1[4], aL0[4], aL1[4];
#pragma unroll
  for (int qt = 0; qt < 4; ++qt) {
    const size_t row16 = (size_t)(Qw + qt * 16 + n16) * 16;
#pragma unroll
    for (int hf = 0; hf < 2; ++hf) {
      const size_t rb = row16 + hf * 8 + quad * 2;
      const f32x4 va = z4[rb];
      const f32x4 vb = z4[rb + 1];
      half8 H, L;
#pragma unroll
      for (int e = 0; e < 4; ++e) {
        const float fa = va[e], fb = vb[e];
        const _Float16 ha = (_Float16)fa, hb = (_Float16)fb;
        H[e] = ha; H[e + 4] = hb;
        L[e] = (_Float16)(fa - (float)ha);
        L[e + 4] = (_Float16)(fb - (float)hb);
      }
      if (hf == 0) { aH0[qt] = H; aL0[qt] = L; }
      else         { aH1[qt] = H; aL1[qt] = L; }
    }
  }

  float best[4][4];
  int bidx[4][4];
#pragma unroll
  for (int qt = 0; qt < 4; ++qt)
#pragma unroll
    for (int r = 0; r < 4; ++r) {
      best[qt][r] = -3.4e38f;
      bidx[qt][r] = 0;
    }

  asm volatile("s_waitcnt vmcnt(0) lgkmcnt(0)" ::: "memory");
  __builtin_amdgcn_s_barrier();
  asm volatile("" ::: "memory");

  for (int g = 0; g < NGROUP; ++g) {
    const int C0 = split * CSPLIT + g * GROUP;
    const _Float16* __restrict__ buf = Bs + (g & 1) * IMGH;

    if (g + 1 < NGROUP) {
      // issue next group's DMA into the other buffer. Safe: the barrier at
      // the end of iteration g-1 guarantees all waves finished reading it.
      const _Float16* gimg = Cxs + (size_t)(split * NGROUP + g + 1) * IMGH;
      _Float16* nbuf = Bs + ((g + 1) & 1) * IMGH;
#pragma unroll
      for (int p = 0; p < 4; ++p) {
        const int off = (t + 256 * p) * 8;
        async_copy16(gimg + off, nbuf + off);
      }
      // oldest-first retire: waits this wave's group-g DMAs, leaves the 4
      // just-issued in flight. No other VMEM ops exist in the loop.
      asm volatile("s_waitcnt vmcnt(4)" ::: "memory");
    } else {
      asm volatile("s_waitcnt vmcnt(0)" ::: "memory");
    }
    __builtin_amdgcn_s_barrier();
    asm volatile("" ::: "memory");

    const half8* __restrict__ Bs8 = (const half8*)buf;
    const float* __restrict__ nhg = nh + g * GROUP;
    __builtin_amdgcn_s_setprio(1);
#pragma unroll
    for (int tt = 0; tt < NTILE; ++tt) {
      const int base = tt * 4 * 64 + quad * 16;
      const half8 b0 = Bs8[base + (n16 ^ quad)];              // Ch k[0,32)
      const half8 b1 = Bs8[base + 64 + (n16 ^ (4 + quad))];   // Ch k[32,64)
      const half8 b2 = Bs8[base + 128 + (n16 ^ quad)];        // Cl k[0,32)
      const half8 b3 = Bs8[base + 192 + (n16 ^ (4 + quad))];  // Cl k[32,64)
      const int c = C0 + tt * 16 + n16;
      const float nc = nhg[tt * 16 + n16];
      const f32x4 ncv = {nc, nc, nc, nc};
#pragma unroll
      for (int qt = 0; qt < 4; ++qt) {
        // first MFMA reads C=ncv, writes D=acc (no per-qt init movs)
        f32x4 acc =
            __builtin_amdgcn_mfma_f32_16x16x32_f16(aH0[qt], b0, ncv, 0, 0, 0);
        acc = __builtin_amdgcn_mfma_f32_16x16x32_f16(aH1[qt], b1, acc, 0, 0, 0);
        acc = __builtin_amdgcn_mfma_f32_16x16x32_f16(aH0[qt], b2, acc, 0, 0, 0);
        acc = __builtin_amdgcn_mfma_f32_16x16x32_f16(aH1[qt], b3, acc, 0, 0, 0);
        acc = __builtin_amdgcn_mfma_f32_16x16x32_f16(aL0[qt], b0, acc, 0, 0, 0);
        acc = __builtin_amdgcn_mfma_f32_16x16x32_f16(aL1[qt], b1, acc, 0, 0, 0);
#pragma unroll
        for (int r = 0; r < 4; ++r) {
          const float u = acc[r];
          if (u > best[qt][r]) { best[qt][r] = u; bidx[qt][r] = c; }
        }
      }
    }
    __builtin_amdgcn_s_setprio(0);
    asm volatile("" ::: "memory");
    __builtin_amdgcn_s_barrier();  // all waves done reading buf before the
                                   // DMA two iterations on re-targets it
  }
#pragma unroll
  for (int qt = 0; qt < 4; ++qt)
#pragma unroll
    for (int r = 0; r < 4; ++r) {
      float u = best[qt][r];
      int c = bidx[qt][r];
#pragma unroll
      for (int off = 1; off < 16; off <<= 1) {
        const float u2 = __shfl_xor(u, off, 64);
        const int c2 = __shfl_xor(c, off, 64);
        if (u2 > u || (u2 == u && c2 < c)) { u = u2; c = c2; }
      }
      if (n16 == 0) {
        const int q = Qw + qt * 16 + quad * 4 + r;
        pmax[(size_t)split * NQ + q] = u;
        pidx[(size_t)split * NQ + q] = (unsigned short)c;
      }
    }
}

// q-partitioned: merge partial argmax (16 splits, non-redundant: lane l16
// owns split l16), gather z_q, write idx, scatter-add dw/cnt via global
// atomics, loss partial (non-atomic, one float per block). 16 queries/block.
__global__ __launch_bounds__(256) void k_assign(
    const float* __restrict__ z, const float* __restrict__ cb,
    const float* __restrict__ pmax, const unsigned short* __restrict__ pidx,
    float* __restrict__ out_zq, float* __restrict__ out_idx,
    float* __restrict__ dw, int* __restrict__ cnt,
    float* __restrict__ parts) {
  const int t = threadIdx.x;
  const int lane = t & 63;
  const int w = t >> 6;
  const int l16 = t & 15;        // split index, also dim-quad index
  const int q = blockIdx.x * 16 + (t >> 4);

  float v = pmax[(size_t)l16 * NQ + q];
  int i = (int)pidx[(size_t)l16 * NQ + q];
#pragma unroll
  for (int off = 1; off < 16; off <<= 1) {
    const float v2 = __shfl_xor(v, off, 64);
    const int i2 = __shfl_xor(i, off, 64);
    if (v2 > v || (v2 == v && i2 < i)) { v = v2; i = i2; }
  }
  const int k = i;  // all 16 lanes of the q-group agree

  const f32x4 zv = ((const f32x4*)z)[(size_t)q * 16 + l16];
  const f32x4 cv = ((const f32x4*)cb)[(size_t)k * 16 + l16];
  ((f32x4*)out_zq)[(size_t)q * 16 + l16] = cv;  // z + (z_q - z)

  float sq = 0.f;
#pragma unroll
  for (int e = 0; e < 4; ++e) {
    const float d = zv[e] - cv[e];
    sq = fmaf(d, d, sq);
  }
  // scatter: 4 f32 atomics per thread (coalesced 16B per thread)
#pragma unroll
  for (int e = 0; e < 4; ++e)
    atomicAdd(&dw[(size_t)k * DD + l16 * 4 + e], zv[e]);
  if (l16 == 0) {
    atomicAdd(&cnt[k], 1);
    out_idx[q] = (float)k;  // exact in f32 (k < 8192)
  }

  // loss partial: full-wave sum then block sum
#pragma unroll
  for (int off = 1; off < 64; off <<= 1) sq += __shfl_xor(sq, off, 64);
  __shared__ float ss[4];
  if (lane == 0) ss[w] = sq;
  __syncthreads();
  if (t == 0) parts[blockIdx.x] = ss[0] + ss[1] + ss[2] + ss[3];
}

// grid-stride EMA/normalize pass over K x D. One f32x4 per thread; 512
// blocks x 256 threads = exactly K*D/4. Block 0 reduces the loss partials.
__global__ __launch_bounds__(256) void k_ema(
    const float* __restrict__ ema_cs, const float* __restrict__ ema_ws,
    const float* __restrict__ dw, const int* __restrict__ cnt,
    const float* __restrict__ epart, const float* __restrict__ parts,
    float* __restrict__ out_ncs, float* __restrict__ out_ncb,
    float* __restrict__ out_nws, float* __restrict__ out_loss) {
  const int t = threadIdx.x;
  const int gid = blockIdx.x * 256 + t;
  const int k = gid >> 4;
  const int l16 = gid & 15;

  // n = 0.99*sum(ema_cs) + 0.01*NQ  (sum(counts) == NQ exactly)
  float esum = 0.f;
#pragma unroll
  for (int b = 0; b < 32; ++b) esum += epart[b];
  const float n = 0.99f * esum + 0.01f * 16384.0f;

  const float cs = 0.99f * ema_cs[k] + 0.01f * (float)cnt[k];
  const float smoothed = (cs + 1e-5f) / (n + (float)KC * 1e-5f) * n;

  const f32x4 dwv = ((const f32x4*)dw)[gid];
  const f32x4 ew = ((const f32x4*)ema_ws)[gid];
  f32x4 nws, ncb;
#pragma unroll
  for (int e = 0; e < 4; ++e) {
    nws[e] = 0.99f * ew[e] + 0.01f * dwv[e];
    ncb[e] = nws[e] / smoothed;
  }
  ((f32x4*)out_nws)[gid] = nws;
  ((f32x4*)out_ncb)[gid] = ncb;
  if (l16 == 0) out_ncs[k] = cs;

  if (blockIdx.x == 0) {
    float s = 0.f;
    for (int i = t; i < 1024; i += 256) s += parts[i];
#pragma unroll
    for (int off = 1; off < 64; off <<= 1) s += __shfl_xor(s, off, 64);
    __shared__ float ls[4];
    if ((t & 63) == 0) ls[t >> 6] = s;
    __syncthreads();
    if (t == 0)
      *out_loss = 1.25f * (ls[0] + ls[1] + ls[2] + ls[3]) *
                  (1.0f / 1048576.0f);
  }
}

extern "C" void kernel_launch(void* const* d_in, const int* in_sizes, int n_in,
                              void* d_out, int out_size, void* d_ws,
                              size_t ws_size, hipStream_t stream) {
  const float* z = (const float*)d_in[0];
  const float* cb = (const float*)d_in[1];
  const float* ema_cs = (const float*)d_in[2];
  const float* ema_ws = (const float*)d_in[3];

  float* out = (float*)d_out;
  float* zq_out = out;              // 1048576
  float* loss_out = out + 1048576;  // 1
  float* idx_out = out + 1048577;   // 16384
  float* ncb_out = out + 1064961;   // 524288
  float* ncs_out = out + 1589249;   // 8192
  float* nws_out = out + 1597441;   // 524288

  float* ws = (float*)d_ws;
  float* nhcn = ws;                                       // 8192
  float* epart = ws + 8192;                               // 32
  float* parts = ws + 8224;                               // 1024
  float* pmax = ws + 16384;                               // 262144
  unsigned short* pidx = (unsigned short*)(ws + 278528);  // 262144 u16
  int* cnt = (int*)(ws + 409600);                         // 8192 int
  float* dw = ws + 417792;                                // 524288
  _Float16* Cxs = (_Float16*)(ws + 942080);               // 1048576 halves

  k_prep<<<KC * 16 / 256, 256, 0, stream>>>(cb, ema_cs, Cxs, nhcn, epart, dw,
                                            cnt);
  k_mfma<<<dim3(NQ / 256, NSPLIT), 256, 0, stream>>>(z, Cxs, nhcn, pmax, pidx);
  k_assign<<<NQ / 16, 256, 0, stream>>>(z, cb, pmax, pidx, zq_out, idx_out, dw,
                                        cnt, parts);
  k_ema<<<KC * DD / 4 / 256, 256, 0, stream>>>(ema_cs, ema_ws, dw, cnt, epart,
                                               parts, ncs_out, ncb_out,
                                               nws_out, loss_out);
}

// Round 7
// 146.055 us; speedup vs baseline: 1.0511x; 1.0511x over previous
//
#include <hip/hip_runtime.h>
#include <hip/hip_bf16.h>

// z: (8,2048,64) f32 -> N=16384, D=64 ; codebook: (8192,64) f32
// outputs (f32, concat): z_q_st[1048576], vq_loss[1], idx[16384],
//   new_codebook[524288], new_cs[8192], new_ws[524288]
//
// Distance argmin via f16-split MFMA: x = xh + xl. dot(x,c) ~= Xh.Ch + Xh.Cl
// + Xl.Ch. argmin ||x-c||^2 == argmax (dot - 0.5||c||^2); -0.5||c||^2 is
// folded into the first MFMA's C operand. Codebook preprocessed ONCE into a
// swizzled f16-split image (k_prep) -> k_mfma stages via global_load_lds.
//
// R7: recombination of proven-best pieces. Cross-round data: R2's k_mfma
// config (GROUP=64, NSPLIT=8, 2 q-tiles/wave, dbuf + counted vmcnt(4),
// launch_bounds(256,4)) = 52.0 us, best measured; every departure regressed
// (GROUP=32: 62.4, 4qt: 62.3, occupancy pushes: spill disasters). R4/R5's
// atomic-scatter tail is worth ~8 us of residual (97.7 -> 89.7). R5/R6
// paired the better tail with a worse k_mfma; R7 pairs best with best.

#define NQ 16384
#define KC 8192
#define DD 64
#define NSPLIT 8
#define CSPLIT (KC / NSPLIT)     // 1024 codes per block job
#define GROUP 64                 // codes staged in LDS per barrier
#define NGROUP (CSPLIT / GROUP)  // 16
#define NTILE (GROUP / 16)       // 4 MFMA c-tiles per staged group
#define IMGH 8192                // halves per group image (16 KB)

typedef _Float16 half8 __attribute__((ext_vector_type(8)));
typedef _Float16 half4v __attribute__((ext_vector_type(4)));
typedef float f32x4 __attribute__((ext_vector_type(4)));
typedef unsigned int u32;

__device__ __forceinline__ void async_copy16(const _Float16* g, _Float16* l) {
  __builtin_amdgcn_global_load_lds(
      (const __attribute__((address_space(1))) u32*)(const void*)g,
      (__attribute__((address_space(3))) u32*)(void*)l, 16, 0, 0);
}

// ---------------- workspace layout (floats) ----------------
// [0)        nhcn    8192    (-0.5*||c||^2)
// [8192)     epart   32      (ema_cs partial sums, non-atomic)
// [8224)     parts   1024    (loss partials, one per k_assign block)
// [16384)    pmax    131072  (8 x 16384 partial max-u)
// [147456)   pidx    131072 u16 = 65536 f32
// [212992)   cnt     8192    (int, atomic counts)
// [221184)   dw      524288  (atomic scatter sums)
// [745472)   Cxs     524288  f32 = 1048576 halves (128 group images x 16 KB)

// k_prep: swizzled f16-split codebook image + nhcn + ema partials + zeroing
// of the dw/cnt atomic accumulators.
// thread = (code c, j4) ; c = gid>>4, j4 = gid&15 covers f32x4 d=4*j4..
__global__ __launch_bounds__(256) void k_prep(
    const float* __restrict__ cb, const float* __restrict__ ema_cs,
    _Float16* __restrict__ Cxs, float* __restrict__ nhcn,
    float* __restrict__ epart, float* __restrict__ dw, int* __restrict__ cnt) {
  const int t = threadIdx.x;
  const int gid = blockIdx.x * 256 + t;
  const int c = gid >> 4;
  const int j4 = gid & 15;

  // zero atomic accumulators for this iteration
  ((f32x4*)dw)[gid] = f32x4{0.f, 0.f, 0.f, 0.f};
  if (gid < KC) cnt[gid] = 0;

  const f32x4 v = ((const f32x4*)cb)[gid];
  half4v hh, ll;
  float s = 0.f;
#pragma unroll
  for (int e = 0; e < 4; ++e) {
    const float f = v[e];
    const _Float16 h = (_Float16)f;
    hh[e] = h;
    ll[e] = (_Float16)(f - (float)h);
    s = fmaf(f, f, s);
  }
  // swizzled slot (same formula as the LDS-consumer in k_mfma)
  const int r = c & (GROUP - 1);   // row in group
  const int tt = r >> 4;
  const int n = r & 15;
  const int q = (j4 >> 1) & 3;
  const int ihalf = j4 & 1;
  const int frh = j4 >> 3;
  const int fs = frh * 4 + q;
  const int nw = n ^ fs;
  _Float16* img = Cxs + (size_t)(c / GROUP) * IMGH;
  *(half4v*)(img + ((size_t)((tt * 4 + frh) * 64 + q * 16 + nw)) * 8 +
             ihalf * 4) = hh;
  *(half4v*)(img + ((size_t)((tt * 4 + frh + 2) * 64 + q * 16 + nw)) * 8 +
             ihalf * 4) = ll;

  // row sumsq: reduce across the 16 lanes of this row (lanes j4=0..15)
#pragma unroll
  for (int off = 1; off < 16; off <<= 1) s += __shfl_xor(s, off, 64);
  if (j4 == 0) nhcn[c] = -0.5f * s;

  // ema partials: blocks 0..31 each reduce 256 values (non-atomic write)
  if (blockIdx.x < 32) {
    float su = ema_cs[blockIdx.x * 256 + t];
#pragma unroll
    for (int off = 1; off < 64; off <<= 1) su += __shfl_xor(su, off, 64);
    __shared__ float ss[4];
    if ((t & 63) == 0) ss[t >> 6] = su;
    __syncthreads();
    if (t == 0) epart[blockIdx.x] = ss[0] + ss[1] + ss[2] + ss[3];
  }
}

// MFMA argmax. 256-thread block = 4 waves x 32 queries (2 q-tiles each);
// block job = 1024 codes (split). Double-buffered global_load_lds staging
// of 16 KB group images; counted vmcnt(4) keeps next group's DMA in flight
// across the barrier. nhcn staged once to LDS -> no VMEM in the K-loop
// besides the DMAs. 36 KB LDS, ~52 VGPR (launch_bounds(256,4) — do NOT
// promise more: min-waves>=8 caps VGPR at 64 and collapses the allocator
// to 32 VGPR + ~1 GB scratch spills, R3/R4).
__global__ __launch_bounds__(256, 4) void k_mfma(
    const float* __restrict__ z, const _Float16* __restrict__ Cxs,
    const float* __restrict__ nhcn, float* __restrict__ pmax,
    unsigned short* __restrict__ pidx) {
  __shared__ _Float16 Bs[2 * IMGH];  // 32 KB (double buffer)
  __shared__ float nh[CSPLIT];       // 4 KB
  const int t = threadIdx.x;
  const int lane = t & 63;
  const int w = t >> 6;
  const int split = blockIdx.y;
  const int Qw = blockIdx.x * 128 + w * 32;
  const int n16 = lane & 15;
  const int quad = lane >> 4;

  // nhcn for this split -> LDS (one f32x4 per thread)
  const f32x4 nhv = ((const f32x4*)(nhcn + split * CSPLIT))[t];

  // prologue: stage group 0 into buffer 0
  {
    const _Float16* gimg = Cxs + (size_t)(split * NGROUP) * IMGH;
#pragma unroll
    for (int p = 0; p < 4; ++p) {
      const int off = (t + 256 * p) * 8;  // halves
      async_copy16(gimg + off, Bs + off);
    }
  }
  ((f32x4*)nh)[t] = nhv;

  // A-frags: z rows -> f16 split in registers (layout: lane holds
  // A[m=lane&15][k=(lane>>4)*8+j]; frag hf covers k/d in [32*hf, 32*hf+32)).
  const f32x4* __restrict__ z4 = (const f32x4*)z;
  half8 aH0[2], aH1[2], aL0[2], aL1[2];
#pragma unroll
  for (int qt = 0; qt < 2; ++qt) {
    const size_t row16 = (size_t)(Qw + qt * 16 + n16) * 16;
#pragma unroll
    for (int hf = 0; hf < 2; ++hf) {
      const size_t rb = row16 + hf * 8 + quad * 2;
      const f32x4 va = z4[rb];
      const f32x4 vb = z4[rb + 1];
      half8 H, L;
#pragma unroll
      for (int e = 0; e < 4; ++e) {
        const float fa = va[e], fb = vb[e];
        const _Float16 ha = (_Float16)fa, hb = (_Float16)fb;
        H[e] = ha; H[e + 4] = hb;
        L[e] = (_Float16)(fa - (float)ha);
        L[e + 4] = (_Float16)(fb - (float)hb);
      }
      if (hf == 0) { aH0[qt] = H; aL0[qt] = L; }
      else         { aH1[qt] = H; aL1[qt] = L; }
    }
  }

  float best[2][4];
  int bidx[2][4];
#pragma unroll
  for (int qt = 0; qt < 2; ++qt)
#pragma unroll
    for (int r = 0; r < 4; ++r) {
      best[qt][r] = -3.4e38f;
      bidx[qt][r] = 0;
    }

  asm volatile("s_waitcnt vmcnt(0) lgkmcnt(0)" ::: "memory");
  __builtin_amdgcn_s_barrier();
  asm volatile("" ::: "memory");

  for (int g = 0; g < NGROUP; ++g) {
    const int C0 = split * CSPLIT + g * GROUP;
    const _Float16* __restrict__ buf = Bs + (g & 1) * IMGH;

    if (g + 1 < NGROUP) {
      // issue next group's DMA into the other buffer. Safe: the barrier at
      // the end of iteration g-1 guarantees all waves finished reading it.
      const _Float16* gimg = Cxs + (size_t)(split * NGROUP + g + 1) * IMGH;
      _Float16* nbuf = Bs + ((g + 1) & 1) * IMGH;
#pragma unroll
      for (int p = 0; p < 4; ++p) {
        const int off = (t + 256 * p) * 8;
        async_copy16(gimg + off, nbuf + off);
      }
      // oldest-first retire: waits this wave's group-g DMAs, leaves the 4
      // just-issued in flight. No other VMEM ops exist in the loop.
      asm volatile("s_waitcnt vmcnt(4)" ::: "memory");
    } else {
      asm volatile("s_waitcnt vmcnt(0)" ::: "memory");
    }
    __builtin_amdgcn_s_barrier();
    asm volatile("" ::: "memory");

    const half8* __restrict__ Bs8 = (const half8*)buf;
    const float* __restrict__ nhg = nh + g * GROUP;
    __builtin_amdgcn_s_setprio(1);
#pragma unroll
    for (int tt = 0; tt < NTILE; ++tt) {
      const int base = tt * 4 * 64 + quad * 16;
      const half8 b0 = Bs8[base + (n16 ^ quad)];              // Ch k[0,32)
      const half8 b1 = Bs8[base + 64 + (n16 ^ (4 + quad))];   // Ch k[32,64)
      const half8 b2 = Bs8[base + 128 + (n16 ^ quad)];        // Cl k[0,32)
      const half8 b3 = Bs8[base + 192 + (n16 ^ (4 + quad))];  // Cl k[32,64)
      const int c = C0 + tt * 16 + n16;
      const float nc = nhg[tt * 16 + n16];
      const f32x4 ncv = {nc, nc, nc, nc};
#pragma unroll
      for (int qt = 0; qt < 2; ++qt) {
        // first MFMA reads C=ncv, writes D=acc (no per-qt init movs)
        f32x4 acc =
            __builtin_amdgcn_mfma_f32_16x16x32_f16(aH0[qt], b0, ncv, 0, 0, 0);
        acc = __builtin_amdgcn_mfma_f32_16x16x32_f16(aH1[qt], b1, acc, 0, 0, 0);
        acc = __builtin_amdgcn_mfma_f32_16x16x32_f16(aH0[qt], b2, acc, 0, 0, 0);
        acc = __builtin_amdgcn_mfma_f32_16x16x32_f16(aH1[qt], b3, acc, 0, 0, 0);
        acc = __builtin_amdgcn_mfma_f32_16x16x32_f16(aL0[qt], b0, acc, 0, 0, 0);
        acc = __builtin_amdgcn_mfma_f32_16x16x32_f16(aL1[qt], b1, acc, 0, 0, 0);
#pragma unroll
        for (int r = 0; r < 4; ++r) {
          const float u = acc[r];
          if (u > best[qt][r]) { best[qt][r] = u; bidx[qt][r] = c; }
        }
      }
    }
    __builtin_amdgcn_s_setprio(0);
    asm volatile("" ::: "memory");
    __builtin_amdgcn_s_barrier();  // all waves done reading buf before the
                                   // DMA two iterations on re-targets it
  }
#pragma unroll
  for (int qt = 0; qt < 2; ++qt)
#pragma unroll
    for (int r = 0; r < 4; ++r) {
      float u = best[qt][r];
      int c = bidx[qt][r];
#pragma unroll
      for (int off = 1; off < 16; off <<= 1) {
        const float u2 = __shfl_xor(u, off, 64);
        const int c2 = __shfl_xor(c, off, 64);
        if (u2 > u || (u2 == u && c2 < c)) { u = u2; c = c2; }
      }
      if (n16 == 0) {
        const int q = Qw + qt * 16 + quad * 4 + r;
        pmax[(size_t)split * NQ + q] = u;
        pidx[(size_t)split * NQ + q] = (unsigned short)c;
      }
    }
}

// q-partitioned: merge partial argmax (8 splits; lane l16 reads split
// l16&7 — each split read twice, harmless), gather z_q, write idx,
// scatter-add dw/cnt via global atomics, loss partial (non-atomic, one
// float per block). 16 queries/block.
__global__ __launch_bounds__(256) void k_assign(
    const float* __restrict__ z, const float* __restrict__ cb,
    const float* __restrict__ pmax, const unsigned short* __restrict__ pidx,
    float* __restrict__ out_zq, float* __restrict__ out_idx,
    float* __restrict__ dw, int* __restrict__ cnt,
    float* __restrict__ parts) {
  const int t = threadIdx.x;
  const int lane = t & 63;
  const int w = t >> 6;
  const int l16 = t & 15;        // dim-quad index
  const int s = l16 & 7;         // split index (8 splits)
  const int q = blockIdx.x * 16 + (t >> 4);

  float v = pmax[(size_t)s * NQ + q];
  int i = (int)pidx[(size_t)s * NQ + q];
#pragma unroll
  for (int off = 1; off < 8; off <<= 1) {
    const float v2 = __shfl_xor(v, off, 64);
    const int i2 = __shfl_xor(i, off, 64);
    if (v2 > v || (v2 == v && i2 < i)) { v = v2; i = i2; }
  }
  const int k = i;  // all 16 lanes of the q-group agree

  const f32x4 zv = ((const f32x4*)z)[(size_t)q * 16 + l16];
  const f32x4 cv = ((const f32x4*)cb)[(size_t)k * 16 + l16];
  ((f32x4*)out_zq)[(size_t)q * 16 + l16] = cv;  // z + (z_q - z)

  float sq = 0.f;
#pragma unroll
  for (int e = 0; e < 4; ++e) {
    const float d = zv[e] - cv[e];
    sq = fmaf(d, d, sq);
  }
  // scatter: 4 f32 atomics per thread (coalesced 16B per thread)
#pragma unroll
  for (int e = 0; e < 4; ++e)
    atomicAdd(&dw[(size_t)k * DD + l16 * 4 + e], zv[e]);
  if (l16 == 0) {
    atomicAdd(&cnt[k], 1);
    out_idx[q] = (float)k;  // exact in f32 (k < 8192)
  }

  // loss partial: full-wave sum then block sum
#pragma unroll
  for (int off = 1; off < 64; off <<= 1) sq += __shfl_xor(sq, off, 64);
  __shared__ float ss[4];
  if (lane == 0) ss[w] = sq;
  __syncthreads();
  if (t == 0) parts[blockIdx.x] = ss[0] + ss[1] + ss[2] + ss[3];
}

// grid-stride EMA/normalize pass over K x D. One f32x4 per thread; 512
// blocks x 256 threads = exactly K*D/4. Block 0 reduces the loss partials.
__global__ __launch_bounds__(256) void k_ema(
    const float* __restrict__ ema_cs, const float* __restrict__ ema_ws,
    const float* __restrict__ dw, const int* __restrict__ cnt,
    const float* __restrict__ epart, const float* __restrict__ parts,
    float* __restrict__ out_ncs, float* __restrict__ out_ncb,
    float* __restrict__ out_nws, float* __restrict__ out_loss) {
  const int t = threadIdx.x;
  const int gid = blockIdx.x * 256 + t;
  const int k = gid >> 4;
  const int l16 = gid & 15;

  // n = 0.99*sum(ema_cs) + 0.01*NQ  (sum(counts) == NQ exactly)
  float esum = 0.f;
#pragma unroll
  for (int b = 0; b < 32; ++b) esum += epart[b];
  const float n = 0.99f * esum + 0.01f * 16384.0f;

  const float cs = 0.99f * ema_cs[k] + 0.01f * (float)cnt[k];
  const float smoothed = (cs + 1e-5f) / (n + (float)KC * 1e-5f) * n;

  const f32x4 dwv = ((const f32x4*)dw)[gid];
  const f32x4 ew = ((const f32x4*)ema_ws)[gid];
  f32x4 nws, ncb;
#pragma unroll
  for (int e = 0; e < 4; ++e) {
    nws[e] = 0.99f * ew[e] + 0.01f * dwv[e];
    ncb[e] = nws[e] / smoothed;
  }
  ((f32x4*)out_nws)[gid] = nws;
  ((f32x4*)out_ncb)[gid] = ncb;
  if (l16 == 0) out_ncs[k] = cs;

  if (blockIdx.x == 0) {
    float s = 0.f;
    for (int i = t; i < 1024; i += 256) s += parts[i];
#pragma unroll
    for (int off = 1; off < 64; off <<= 1) s += __shfl_xor(s, off, 64);
    __shared__ float ls[4];
    if ((t & 63) == 0) ls[t >> 6] = s;
    __syncthreads();
    if (t == 0)
      *out_loss = 1.25f * (ls[0] + ls[1] + ls[2] + ls[3]) *
                  (1.0f / 1048576.0f);
  }
}

extern "C" void kernel_launch(void* const* d_in, const int* in_sizes, int n_in,
                              void* d_out, int out_size, void* d_ws,
                              size_t ws_size, hipStream_t stream) {
  const float* z = (const float*)d_in[0];
  const float* cb = (const float*)d_in[1];
  const float* ema_cs = (const float*)d_in[2];
  const float* ema_ws = (const float*)d_in[3];

  float* out = (float*)d_out;
  float* zq_out = out;              // 1048576
  float* loss_out = out + 1048576;  // 1
  float* idx_out = out + 1048577;   // 16384
  float* ncb_out = out + 1064961;   // 524288
  float* ncs_out = out + 1589249;   // 8192
  float* nws_out = out + 1597441;   // 524288

  float* ws = (float*)d_ws;
  float* nhcn = ws;                                       // 8192
  float* epart = ws + 8192;                               // 32
  float* parts = ws + 8224;                               // 1024
  float* pmax = ws + 16384;                               // 131072
  unsigned short* pidx = (unsigned short*)(ws + 147456);  // 131072 u16
  int* cnt = (int*)(ws + 212992);                         // 8192 int
  float* dw = ws + 221184;                                // 524288
  _Float16* Cxs = (_Float16*)(ws + 745472);               // 1048576 halves

  k_prep<<<KC * 16 / 256, 256, 0, stream>>>(cb, ema_cs, Cxs, nhcn, epart, dw,
                                            cnt);
  k_mfma<<<dim3(NQ / 128, NSPLIT), 256, 0, stream>>>(z, Cxs, nhcn, pmax, pidx);
  k_assign<<<NQ / 16, 256, 0, stream>>>(z, cb, pmax, pidx, zq_out, idx_out, dw,
                                        cnt, parts);
  k_ema<<<KC * DD / 4 / 256, 256, 0, stream>>>(ema_cs, ema_ws, dw, cnt, epart,
                                               parts, ncs_out, ncb_out,
                                               nws_out, loss_out);
}